// Round 1
// baseline (1469.978 us; speedup 1.0000x reference)
//
#include <hip/hip_runtime.h>
#include <math.h>

#define BB 8
#define CC 256
#define HH 224
#define WW 224
#define HWSZ (HH * WW)
#define C4 64

__device__ __forceinline__ float sigmoidf_(float z) {
    return 1.0f / (1.0f + __expf(-z));
}

// ---------------------------------------------------------------------------
// K1: one full pass over x.
//  - per-pixel spatial logit: dot over C (accumulated in registers, each
//    thread owns 2 fixed pixels) -> sigmoid -> spatial_sig[b*HW + p]
//  - per-(b,c) sum over HW for the channel-MLP average: wave-reduce the
//    block's 2-pixel contributions, lane0 atomicAdd into avgsum[b*C+c].
// grid (98, B), block 256: 98 * 256 threads * 2 px = 50176 = HW exactly.
// ---------------------------------------------------------------------------
__global__ __launch_bounds__(256) void k1_spatial_avg(
    const float* __restrict__ x, const float* __restrict__ sw,
    const float* __restrict__ sb, float* __restrict__ spatial_sig,
    float* __restrict__ avgsum)
{
    const int b = blockIdx.y;
    const int p2 = blockIdx.x * 256 + threadIdx.x;   // float2 index in [0, HW/2)
    const float2* xp = (const float2*)(x + (size_t)b * CC * HWSZ) + p2;
    float* avgrow = avgsum + b * CC;
    const int lane = threadIdx.x & 63;

    float s0 = 0.f, s1 = 0.f;
    #pragma unroll 4
    for (int c = 0; c < CC; ++c) {
        float2 v = xp[(size_t)c * (HWSZ / 2)];
        float wgt = sw[c];                // uniform -> scalar load
        s0 = fmaf(v.x, wgt, s0);
        s1 = fmaf(v.y, wgt, s1);
        float part = v.x + v.y;           // contribution to sum over HW
        #pragma unroll
        for (int off = 32; off > 0; off >>= 1)
            part += __shfl_xor(part, off, 64);
        if (lane == 0) atomicAdd(&avgrow[c], part);
    }
    const float bias = sb[0];
    float2 o;
    o.x = sigmoidf_(s0 + bias);
    o.y = sigmoidf_(s1 + bias);
    ((float2*)(spatial_sig + (size_t)b * HWSZ))[p2] = o;
}

// ---------------------------------------------------------------------------
// K2: channel MLP. grid (B), block 64.
// h = relu(avg @ cc1_w.T + cc1_b)  (64 outs, one per thread)
// channel = sigmoid(h @ cc2_w.T + cc2_b)  (256 outs, 4 per thread)
// ---------------------------------------------------------------------------
__global__ __launch_bounds__(64) void k2_channel(
    const float* __restrict__ avgsum, const float* __restrict__ w1,
    const float* __restrict__ b1, const float* __restrict__ w2,
    const float* __restrict__ b2, float* __restrict__ channel_sig)
{
    __shared__ float avg[CC];
    __shared__ float hsh[C4];
    const int b = blockIdx.x;
    const int t = threadIdx.x;
    const float inv = 1.0f / (float)HWSZ;
    for (int c = t; c < CC; c += 64) avg[c] = avgsum[b * CC + c] * inv;
    __syncthreads();

    float acc = b1[t];
    const float* wrow = w1 + t * CC;     // cc1_w is (64, 256) row-major
    #pragma unroll 4
    for (int c = 0; c < CC; ++c) acc = fmaf(avg[c], wrow[c], acc);
    hsh[t] = fmaxf(acc, 0.f);
    __syncthreads();

    for (int c = t; c < CC; c += 64) {
        float a = b2[c];
        const float* w2r = w2 + c * C4;  // cc2_w is (256, 64) row-major
        #pragma unroll
        for (int o = 0; o < C4; ++o) a = fmaf(hsh[o], w2r[o], a);
        channel_sig[b * CC + c] = sigmoidf_(a);
    }
}

// ---------------------------------------------------------------------------
// K3: output pass. Each thread: one float4 of one row of one (b,c) plane.
// edge_raw = 8*center - sum(8 neighbors), zero padding =>
//          = 9*center - sum(3x3 window).
// out = x * spatial * channel * sigmoid(edge_raw)
// grid (H/4, B*C), block (64, 4). Lanes 56..63 idle (56 float4 per row).
// ---------------------------------------------------------------------------
__global__ __launch_bounds__(256) void k3_out(
    const float* __restrict__ x, const float* __restrict__ spatial_sig,
    const float* __restrict__ channel_sig, float* __restrict__ out)
{
    const int bc = blockIdx.y;           // b*C + c
    const int b  = bc >> 8;
    const int r  = blockIdx.x * 4 + threadIdx.y;
    const int q  = threadIdx.x;
    if (q >= 56) return;
    const int col0 = q * 4;

    const float* plane = x + (size_t)bc * HWSZ;
    const float* rowc  = plane + r * WW;

    float t6[6], c6[6], d6[6];
    {
        float4 v = *(const float4*)(rowc + col0);
        c6[0] = (col0 > 0) ? rowc[col0 - 1] : 0.f;
        c6[1] = v.x; c6[2] = v.y; c6[3] = v.z; c6[4] = v.w;
        c6[5] = (col0 + 4 < WW) ? rowc[col0 + 4] : 0.f;
    }
    if (r > 0) {
        const float* rt = rowc - WW;
        float4 v = *(const float4*)(rt + col0);
        t6[0] = (col0 > 0) ? rt[col0 - 1] : 0.f;
        t6[1] = v.x; t6[2] = v.y; t6[3] = v.z; t6[4] = v.w;
        t6[5] = (col0 + 4 < WW) ? rt[col0 + 4] : 0.f;
    } else {
        t6[0] = t6[1] = t6[2] = t6[3] = t6[4] = t6[5] = 0.f;
    }
    if (r < HH - 1) {
        const float* rb = rowc + WW;
        float4 v = *(const float4*)(rb + col0);
        d6[0] = (col0 > 0) ? rb[col0 - 1] : 0.f;
        d6[1] = v.x; d6[2] = v.y; d6[3] = v.z; d6[4] = v.w;
        d6[5] = (col0 + 4 < WW) ? rb[col0 + 4] : 0.f;
    } else {
        d6[0] = d6[1] = d6[2] = d6[3] = d6[4] = d6[5] = 0.f;
    }

    const float ch = channel_sig[bc];
    float4 sp = *(const float4*)(spatial_sig + (size_t)b * HWSZ + r * WW + col0);
    float spv[4] = {sp.x, sp.y, sp.z, sp.w};

    float4 o;
    float* op = (float*)&o;
    #pragma unroll
    for (int j = 0; j < 4; ++j) {
        float wt = t6[j] + t6[j + 1] + t6[j + 2];
        float wc = c6[j] + c6[j + 1] + c6[j + 2];
        float wb = d6[j] + d6[j + 1] + d6[j + 2];
        float center = c6[j + 1];
        float edge_raw = 9.f * center - (wt + wc + wb);
        op[j] = center * spv[j] * ch * sigmoidf_(edge_raw);
    }
    *(float4*)(out + (size_t)bc * HWSZ + r * WW + col0) = o;
}

// ---------------------------------------------------------------------------
extern "C" void kernel_launch(void* const* d_in, const int* in_sizes, int n_in,
                              void* d_out, int out_size, void* d_ws, size_t ws_size,
                              hipStream_t stream) {
    const float* x  = (const float*)d_in[0];
    const float* sw = (const float*)d_in[1];
    const float* sb = (const float*)d_in[2];
    const float* w1 = (const float*)d_in[3];
    const float* b1 = (const float*)d_in[4];
    const float* w2 = (const float*)d_in[5];
    const float* b2 = (const float*)d_in[6];
    float* out = (float*)d_out;

    float* spatial_sig = (float*)d_ws;                       // B*HW floats
    float* avgsum      = spatial_sig + (size_t)BB * HWSZ;    // B*C floats
    float* channel_sig = avgsum + BB * CC;                   // B*C floats

    hipMemsetAsync(avgsum, 0, BB * CC * sizeof(float), stream);

    k1_spatial_avg<<<dim3(HWSZ / 512, BB), 256, 0, stream>>>(
        x, sw, sb, spatial_sig, avgsum);
    k2_channel<<<dim3(BB), 64, 0, stream>>>(
        avgsum, w1, b1, w2, b2, channel_sig);
    k3_out<<<dim3(HH / 4, BB * CC), dim3(64, 4), 0, stream>>>(
        x, spatial_sig, channel_sig, out);
}